// Round 2
// baseline (446.050 us; speedup 1.0000x reference)
//
#include <hip/hip_runtime.h>
#include <math.h>

// Problem geometry (fixed by the reference setup_inputs()).
#define HH 512
#define WW 512
#define BATCH 8
#define PIX (HH * WW)            // 262144 pixels per image
#define NCH 16                   // 8 pred channels + 8 target channels (fused skeletonize)
#define NPIX_TOT (NCH * PIX)     // 4,194,304
#define N_ELEM (BATCH * PIX)     // 2,097,152 elements per (8,1,512,512) tensor
#define EPSV 1e-6

// Fused skeletonize tile geometry.
#define TS 64                    // output tile is TS x TS
#define HALO 2
#define IW (TS + 2 * HALO)       // 68: img tile width (halo 2 for erode+max3)
#define EW (TS + 2)              // 66: erode tile width (halo 1 for max3)

// Accumulator layout (doubles in workspace):
//  [0..7]   dice-mask inter (sum p*m)      per batch
//  [8..15]  dice-mask sum p                per batch
//  [16..23] dice-mask sum m                per batch
//  [24..31] dice-skel inter (sum q*s)      per batch
//  [32..39] dice-skel sum q                per batch
//  [40..47] dice-skel sum s                per batch   (doubles as smooth-L1 msum/2)
//  [48] focal-mask sum   [49] focal-junction sum  [50] focal-endpoint sum
//  [51] smooth-L1 sum    [52] uncertainty MSE sum
//  [53..60] cldice sum ps*mask   [61..68] sum ps
//  [69..76] cldice sum ts*p      [77..84] sum ts
#define ACC_COUNT 128
#define ACC_BYTES (ACC_COUNT * sizeof(double))

__device__ __forceinline__ float sigm(float x) { return 1.0f / (1.0f + expf(-x)); }
__device__ __forceinline__ float clamp01(float v) { return fminf(fmaxf(v, 0.0f), 1.0f); }

__device__ __forceinline__ float focal_term(float x, float t) {
    float bce = fmaxf(x, 0.0f) - x * t + log1pf(expf(-fabsf(x)));
    float p   = sigm(x);
    float p_t = p * t + (1.0f - p) * (1.0f - t);
    float a_t = 0.25f * t + 0.75f * (1.0f - t);
    float om  = 1.0f - p_t;
    return a_t * om * om * bce;
}

// Block (256 threads) sum reduction in double; result valid on thread 0.
__device__ __forceinline__ double blockReduceSum(double v, double* sm4) {
    int lane = threadIdx.x & 63, wid = threadIdx.x >> 6;
#pragma unroll
    for (int off = 32; off; off >>= 1) v += __shfl_down(v, off);
    __syncthreads();                 // protect sm4 reuse across successive calls
    if (lane == 0) sm4[wid] = v;
    __syncthreads();
    double r = 0.0;
    if (threadIdx.x == 0) r = sm4[0] + sm4[1] + sm4[2] + sm4[3];
    return r;
}

// ---------------------------------------------------------------------------
// K1: all point-wise losses that don't need the skeletons.
// Grid = 1024 blocks (128 per batch); each block owns 2048 contiguous pixels.
// ---------------------------------------------------------------------------
__global__ __launch_bounds__(256) void k_main_reduce(
    const float* __restrict__ mask_logits, const float* __restrict__ skel_logits,
    const float* __restrict__ unc_logits,  const float* __restrict__ junc_logits,
    const float* __restrict__ endp_logits, const float* __restrict__ aff_pred,
    const float* __restrict__ mask,        const float* __restrict__ skel,
    const float* __restrict__ junc,        const float* __restrict__ endp,
    const float* __restrict__ aff_tgt,     const float* __restrict__ unc,
    double* __restrict__ acc)
{
    __shared__ double sm4[4];
    int b     = blockIdx.x >> 7;          // batch index
    int chunk = blockIdx.x & 127;
    int base  = b * PIX + chunk * 2048;   // flat index into (8,1,512,512)
    int pix0  = chunk * 2048;             // pixel-within-image base

    float q0 = 0, q1 = 0, q2 = 0, q3 = 0, q4 = 0, q5 = 0;
    float q6 = 0, q7 = 0, q8 = 0, q9 = 0, q10 = 0;

#pragma unroll
    for (int k = 0; k < 8; ++k) {
        int off = k * 256 + threadIdx.x;
        int i   = base + off;

        float ml = mask_logits[i], m = mask[i];
        float p  = sigm(ml);
        q0 += p * m; q1 += p; q2 += m;
        q6 += focal_term(ml, m);

        float sl = skel_logits[i], s = skel[i];
        float q  = sigm(sl);
        q3 += q * s; q4 += q; q5 += s;

        q7 += focal_term(junc_logits[i], junc[i]);
        q8 += focal_term(endp_logits[i], endp[i]);

        float ud = sigm(unc_logits[i]) - unc[i];
        q10 += ud * ud;

        // smooth-L1 over 2 affinity channels, mask = skeleton (broadcast)
        int pixi = pix0 + off;
#pragma unroll
        for (int c = 0; c < 2; ++c) {
            int ai  = (b * 2 + c) * PIX + pixi;
            float d = aff_pred[ai] * s - aff_tgt[ai] * s;
            float ad = fabsf(d);
            q9 += (ad < 1.0f) ? 0.5f * d * d : ad - 0.5f;
        }
    }

    double r;
    r = blockReduceSum((double)q0, sm4);  if (threadIdx.x == 0) atomicAdd(&acc[0  + b], r);
    r = blockReduceSum((double)q1, sm4);  if (threadIdx.x == 0) atomicAdd(&acc[8  + b], r);
    r = blockReduceSum((double)q2, sm4);  if (threadIdx.x == 0) atomicAdd(&acc[16 + b], r);
    r = blockReduceSum((double)q3, sm4);  if (threadIdx.x == 0) atomicAdd(&acc[24 + b], r);
    r = blockReduceSum((double)q4, sm4);  if (threadIdx.x == 0) atomicAdd(&acc[32 + b], r);
    r = blockReduceSum((double)q5, sm4);  if (threadIdx.x == 0) atomicAdd(&acc[40 + b], r);
    r = blockReduceSum((double)q6, sm4);  if (threadIdx.x == 0) atomicAdd(&acc[48], r);
    r = blockReduceSum((double)q7, sm4);  if (threadIdx.x == 0) atomicAdd(&acc[49], r);
    r = blockReduceSum((double)q8, sm4);  if (threadIdx.x == 0) atomicAdd(&acc[50], r);
    r = blockReduceSum((double)q9, sm4);  if (threadIdx.x == 0) atomicAdd(&acc[51], r);
    r = blockReduceSum((double)q10, sm4); if (threadIdx.x == 0) atomicAdd(&acc[52], r);
}

// ---------------------------------------------------------------------------
// Fused skeletonize iteration. One block = one 64x64 tile of one channel.
//   LDS: img tile (halo 2, +inf padded OOB) -> erode tile (halo 1, -inf OOB)
//   -> per-pixel: max3(E), delta = relu(img - max3), skeleton update.
// MODE 0 (init):  img loaded as clip(sigmoid(logits)) / clip(mask);
//                 skel = delta; E written as next img.
// MODE 1 (mid):   img from buffer; skel += relu(delta - skel*delta); E written.
// MODE 2 (final): like MODE 1 but nothing written; the final clamped skeleton
//                 feeds the cldice partial sums directly (acc atomics).
// Grid: 16 channels x 64 tiles = 1024 blocks. Channels 0..7 = pred (sigmoid
// of mask_logits), 8..15 = target (mask).
// ---------------------------------------------------------------------------
template<int MODE>
__global__ __launch_bounds__(256) void k_skel_iter(
    const float* __restrict__ in0,    // MODE 0: mask_logits ; else: img buffer
    const float* __restrict__ in1,    // MODE 0: mask ; MODE 2: mask_logits
    const float* __restrict__ in2,    // MODE 2: mask
    float* __restrict__ outE,         // next img (unused in MODE 2)
    float* __restrict__ skel,
    double* __restrict__ acc)
{
    __shared__ float simg[IW * IW];   // 68*68*4 = 18.5 KB
    __shared__ float sE[EW * IW];     // 66 rows, stride 68 = 18.0 KB
    __shared__ double sm4[4];

    const int c    = blockIdx.x >> 6;        // channel 0..15
    const int tile = blockIdx.x & 63;
    const int by   = (tile >> 3) * TS;       // tile origin in image coords
    const int bx   = (tile & 7) * TS;

    // --- Phase 1: load img tile (halo 2), +inf outside the image -----------
    for (int idx = threadIdx.x; idx < IW * IW; idx += 256) {
        int ly = idx / IW, lx = idx - ly * IW;
        int gy = by - HALO + ly, gx = bx - HALO + lx;
        float v = INFINITY;
        if (gy >= 0 && gy < HH && gx >= 0 && gx < WW) {
            int gi = (gy << 9) + gx;
            if (MODE == 0) {
                v = (c < 8) ? clamp01(sigm(in0[c * PIX + gi]))
                            : clamp01(in1[(c - 8) * PIX + gi]);
            } else {
                v = in0[c * PIX + gi];
            }
        }
        simg[idx] = v;
    }
    __syncthreads();

    // --- Phase 2: erode (5-pt cross min; +inf pad is the min identity), ----
    //     -inf at positions outside the image so max3 skips them.
    for (int idx = threadIdx.x; idx < EW * EW; idx += 256) {
        int ey = idx / EW, ex = idx - ey * EW;
        int gy = by - 1 + ey, gx = bx - 1 + ex;
        float e = -INFINITY;
        if (gy >= 0 && gy < HH && gx >= 0 && gx < WW) {
            int ci = (ey + 1) * IW + (ex + 1);   // center in img tile
            float v = simg[ci];
            v = fminf(v, simg[ci - IW]);
            v = fminf(v, simg[ci + IW]);
            v = fminf(v, simg[ci - 1]);
            v = fminf(v, simg[ci + 1]);
            e = v;
        }
        sE[ey * IW + ex] = e;
    }
    __syncthreads();

    // --- Phase 3: max3(E), delta, skeleton update --------------------------
    double t0 = 0.0, t1 = 0.0;                 // MODE 2 cldice partials
    for (int idx = threadIdx.x; idx < TS * TS; idx += 256) {
        int oy = idx >> 6, ox = idx & 63;
        int gy = by + oy, gx = bx + ox;
        int eci = (oy + 1) * IW + (ox + 1);

        float mx = sE[eci - IW - 1];
        mx = fmaxf(mx, sE[eci - IW]);
        mx = fmaxf(mx, sE[eci - IW + 1]);
        mx = fmaxf(mx, sE[eci - 1]);
        mx = fmaxf(mx, sE[eci]);
        mx = fmaxf(mx, sE[eci + 1]);
        mx = fmaxf(mx, sE[eci + IW - 1]);
        mx = fmaxf(mx, sE[eci + IW]);
        mx = fmaxf(mx, sE[eci + IW + 1]);

        float img   = simg[(oy + HALO) * IW + (ox + HALO)];
        float delta = fmaxf(img - mx, 0.0f);

        int gi = c * PIX + (gy << 9) + gx;
        if (MODE != 2) outE[gi] = sE[eci];     // E becomes next iteration's img

        if (MODE == 0) {
            skel[gi] = delta;
        } else if (MODE == 1) {
            float sk = skel[gi];
            skel[gi] = sk + fmaxf(delta - sk * delta, 0.0f);
        } else {
            float sk = skel[gi];
            float ns = clamp01(sk + fmaxf(delta - sk * delta, 0.0f)); // final clip
            int pi   = (gy << 9) + gx;
            if (c < 8) {           // pred skeleton: prec sums vs target mask
                float m = in2[c * PIX + pi];
                t0 += (double)(ns * m);
                t1 += (double)ns;
            } else {               // target skeleton: sens sums vs pred probs
                float p = sigm(in1[(c - 8) * PIX + pi]);
                t0 += (double)(ns * p);
                t1 += (double)ns;
            }
        }
    }

    if (MODE == 2) {
        double r0 = blockReduceSum(t0, sm4);
        double r1 = blockReduceSum(t1, sm4);
        if (threadIdx.x == 0) {
            if (c < 8) { atomicAdd(&acc[53 + c], r0);     atomicAdd(&acc[61 + c], r1); }
            else       { atomicAdd(&acc[69 + c - 8], r0); atomicAdd(&acc[77 + c - 8], r1); }
        }
    }
}

// ---------------------------------------------------------------------------
// K3: combine everything into the scalar loss.
// ---------------------------------------------------------------------------
__global__ void k_finalize(const double* __restrict__ acc, float* __restrict__ out)
{
    if (threadIdx.x != 0 || blockIdx.x != 0) return;
    const double eps = EPSV;
    const double Nd  = (double)N_ELEM;

    double dm = 0, ds = 0, cl = 0, msum = 0;
    for (int b = 0; b < BATCH; ++b) {
        dm += (2.0 * acc[0 + b] + eps) / (acc[8 + b] + acc[16 + b] + eps);
        ds += (2.0 * acc[24 + b] + eps) / (acc[32 + b] + acc[40 + b] + eps);
        double prec = acc[53 + b] / (acc[61 + b] + eps);
        double sens = acc[69 + b] / (acc[77 + b] + eps);
        cl += (2.0 * prec * sens + eps) / (prec + sens + eps);
        msum += acc[40 + b];
    }
    msum *= 2.0;   // skeleton mask broadcast over 2 affinity channels

    double mask_loss = (1.0 - dm / 8.0) + acc[48] / Nd;
    double skel_loss = 1.0 - ds / 8.0;
    double topo      = 1.0 - cl / 8.0;
    double node      = 0.5 * (acc[49] / Nd + acc[50] / Nd);
    double aff       = (msum == 0.0) ? 0.0 : acc[51] / fmax(msum, 1.0);
    double unc       = acc[52] / Nd;

    double total = mask_loss + skel_loss + 0.5 * topo + 0.5 * node + 0.5 * aff + 0.1 * unc;
    out[0] = (float)total;
}

// ---------------------------------------------------------------------------
extern "C" void kernel_launch(void* const* d_in, const int* in_sizes, int n_in,
                              void* d_out, int out_size, void* d_ws, size_t ws_size,
                              hipStream_t stream)
{
    const float* mask_logits = (const float*)d_in[0];
    const float* skel_logits = (const float*)d_in[1];
    const float* unc_logits  = (const float*)d_in[2];
    const float* junc_logits = (const float*)d_in[3];
    const float* endp_logits = (const float*)d_in[4];
    const float* aff_pred    = (const float*)d_in[5];
    const float* mask        = (const float*)d_in[6];
    const float* skel        = (const float*)d_in[7];
    const float* junc        = (const float*)d_in[8];
    const float* endp        = (const float*)d_in[9];
    const float* aff_tgt     = (const float*)d_in[10];
    const float* unc         = (const float*)d_in[11];
    float* out = (float*)d_out;

    char* ws = (char*)d_ws;
    double* acc = (double*)ws;
    float* P0   = (float*)(ws + ACC_BYTES);
    float* P1   = P0 + NPIX_TOT;
    float* SKEL = P1 + NPIX_TOT;
    // ws usage: 1 KiB + 3 * 16 MiB = ~48 MiB

    hipMemsetAsync(acc, 0, ACC_BYTES, stream);

    k_main_reduce<<<1024, 256, 0, stream>>>(
        mask_logits, skel_logits, unc_logits, junc_logits, endp_logits,
        aff_pred, mask, skel, junc, endp, aff_tgt, unc, acc);

    const int SGRID = NCH * 64;  // 1024 blocks: 16 channels x (8x8 tiles)

    // Iter 0: img0 = clip(src) materialized in-register; writes E1 + initial skel.
    k_skel_iter<0><<<SGRID, 256, 0, stream>>>(
        mask_logits, mask, nullptr, P1, SKEL, nullptr);

    // Iters 1..9: img = E_k; write E_{k+1}; skeleton update.
    float* IMG = P1;
    float* OTH = P0;
    for (int it = 0; it < 9; ++it) {
        k_skel_iter<1><<<SGRID, 256, 0, stream>>>(
            IMG, nullptr, nullptr, OTH, SKEL, nullptr);
        float* t = IMG; IMG = OTH; OTH = t;
    }

    // Iter 10 (final): no writes; cldice partial sums straight from registers.
    k_skel_iter<2><<<SGRID, 256, 0, stream>>>(
        IMG, mask_logits, mask, nullptr, SKEL, acc);

    k_finalize<<<1, 64, 0, stream>>>(acc, out);
}